// Round 4
// baseline (103.859 us; speedup 1.0000x reference)
//
#include <hip/hip_runtime.h>
#include <hip/hip_bf16.h>
#include <cstdint>
#include <cstddef>

#define P_ 256
#define L_ 6
#define D_ 300
#define J_ 3072   // P*2*L
#define N_ 4096
#define H_ 256
#define C_ 5
#define KP 320    // K padded to multiple of 32
#define NCH 512   // time chunks (pass 1)
#define CS 8      // steps per chunk: NCH*CS == N_
#define NL1 64    // after level-1 compose (512/8)
#define NL2 8     // after level-2 compose (64/8)

#define SLS 0.62245933120185459f  // sigmoid(0.5)

typedef __attribute__((ext_vector_type(8))) short short8v;  // 8 bf16 (4 VGPRs)
typedef __attribute__((ext_vector_type(4))) float f32x4;

__device__ __forceinline__ float sigmoidf_(float x) { return 1.0f / (1.0f + __expf(-x)); }
__device__ __forceinline__ float bl_(unsigned u) { return __uint_as_float(u << 16); }
__device__ __forceinline__ float bh_(unsigned u) { return __uint_as_float(u & 0xffff0000u); }

// ---------------------------------------------------------------------------
// Prep (fused): gather emb[doc] -> X bf16 [N_][KP]; diags -> Bb bf16 [J_][KP].
// ---------------------------------------------------------------------------
__global__ __launch_bounds__(256) void prep_XB(
    const int* __restrict__ doc, const float* __restrict__ emb,
    const float* __restrict__ diags,
    __hip_bfloat16* __restrict__ X, __hip_bfloat16* __restrict__ Bb)
{
    const int i = blockIdx.x * 256 + threadIdx.x;
    const int NX = N_ * KP;
    if (i < NX) {
        const int n = i / KP, k = i - n * KP;
        float v = (k < D_) ? emb[(size_t)doc[n] * D_ + k] : 0.0f;
        X[i] = __float2bfloat16(v);
    } else {
        const int ii = i - NX;
        const int j = ii / KP, k = ii - j * KP;
        float v = (k < D_) ? diags[(size_t)j * D_ + k] : 0.0f;
        Bb[ii] = __float2bfloat16(v);
    }
}

// ---------------------------------------------------------------------------
// Kernel 1: T = sigmoid(X @ Bb^T + bias) -> bf16 T.
// FULL-K single-stage GEMM: 64x64 tile, K=320 staged whole (40KB A + 40KB B),
// ONE barrier, zero barriers in the MFMA loop, 20 outstanding loads/thread.
// Rule-21 XOR swizzle (c ^= (row&7)<<4) applied on the global SOURCE address
// (LDS dest linear, as global_load_lds requires) and on the ds_read side.
// 4 waves in 2x2 quadrants; each wave 32x32 = 2x2 frags of 16x16x32, 10 ksteps.
// Epilogue: LDS transpose (stride 144B) -> 128B-segment global writes.
// ---------------------------------------------------------------------------
__global__ __launch_bounds__(256) void gemm_fullk(
    const __hip_bfloat16* __restrict__ X, const __hip_bfloat16* __restrict__ Bb,
    const float* __restrict__ bias, __hip_bfloat16* __restrict__ T)
{
    __shared__ char lds[81920];           // As 40960 | Bs 40960 (out-tile reuses As)
    char* AsB = lds;
    char* BsB = lds + 40960;

    const int tid  = threadIdx.x;
    const int lane = tid & 63;
    const int w    = tid >> 6;            // wave 0..3
    const int wr   = w >> 1, wc = w & 1;

    // XCD-aware bijective swizzle: nwg = 3072 = 8 * 384
    const int bid = blockIdx.x;
    const int swz = (bid & 7) * 384 + (bid >> 3);
    const int by  = swz / 48, bx = swz - by * 48;   // 64 m-tiles x 48 j-tiles
    const int m0  = by * 64, j0 = bx * 64;

    const char* Xt = (const char*)(X  + (size_t)m0 * KP);   // contiguous 40KB tile
    const char* Bt = (const char*)(Bb + (size_t)j0 * KP);

    // ---- stage full K: wave w covers LDS bytes [w*10240, +10240), 10x1024B ----
    {
        const int lb = lane * 16;
        #pragma unroll
        for (int i = 0; i < 10; ++i) {
            const int ql  = i * 1024 + lb;        // [0,10240) linear within wave span
            const int r2  = ql / 640;             // row within wave's 16-row span
            const int c   = ql - r2 * 640;        // byte col within row [0,640)
            const int src = w * 10240 + r2 * 640 + (c ^ ((r2 & 7) << 4));
            __builtin_amdgcn_global_load_lds(
                (const __attribute__((address_space(1))) unsigned*)(Xt + src),
                (__attribute__((address_space(3))) unsigned*)(AsB + w * 10240 + i * 1024),
                16, 0, 0);
            __builtin_amdgcn_global_load_lds(
                (const __attribute__((address_space(1))) unsigned*)(Bt + src),
                (__attribute__((address_space(3))) unsigned*)(BsB + w * 10240 + i * 1024),
                16, 0, 0);
        }
    }
    __syncthreads();   // the ONE drain

    // ---- pure LDS + MFMA, no barriers ----
    const int fr   = lane & 15;
    const int kh16 = (lane >> 4) << 4;            // k-half byte offset {0,16,32,48}
    const int ax   = (fr & 7) << 4;               // row-XOR (rows differ by mult of 8)
    const int ra0  = (wr * 32 + fr) * 640;
    const int ra1  = ra0 + 16 * 640;
    const int rb0  = (wc * 32 + fr) * 640;
    const int rb1  = rb0 + 16 * 640;

    f32x4 acc[2][2];
    #pragma unroll
    for (int mi = 0; mi < 2; ++mi)
        #pragma unroll
        for (int ni = 0; ni < 2; ++ni)
            acc[mi][ni] = (f32x4){0.f, 0.f, 0.f, 0.f};

    #pragma unroll
    for (int kt = 0; kt < 10; ++kt) {
        const int cc = (kt * 64 + kh16) ^ ax;
        short8v a0 = *(const short8v*)(AsB + ra0 + cc);
        short8v a1 = *(const short8v*)(AsB + ra1 + cc);
        short8v b0 = *(const short8v*)(BsB + rb0 + cc);
        short8v b1 = *(const short8v*)(BsB + rb1 + cc);
        acc[0][0] = __builtin_amdgcn_mfma_f32_16x16x32_bf16(a0, b0, acc[0][0], 0, 0, 0);
        acc[0][1] = __builtin_amdgcn_mfma_f32_16x16x32_bf16(a0, b1, acc[0][1], 0, 0, 0);
        acc[1][0] = __builtin_amdgcn_mfma_f32_16x16x32_bf16(a1, b0, acc[1][0], 0, 0, 0);
        acc[1][1] = __builtin_amdgcn_mfma_f32_16x16x32_bf16(a1, b1, acc[1][1], 0, 0, 0);
    }

    // ---- epilogue: bias+sigmoid -> LDS out-tile [64][72] bf16 (144B stride) ----
    float bj[2];
    #pragma unroll
    for (int ni = 0; ni < 2; ++ni)
        bj[ni] = bias[j0 + wc * 32 + ni * 16 + fr];

    __syncthreads();   // all ds_reads of As/Bs complete before overwrite
    const int kh = lane >> 4;
    #pragma unroll
    for (int mi = 0; mi < 2; ++mi) {
        #pragma unroll
        for (int ni = 0; ni < 2; ++ni) {
            const int col = wc * 32 + ni * 16 + fr;
            #pragma unroll
            for (int r = 0; r < 4; ++r) {
                const int row = wr * 32 + mi * 16 + kh * 4 + r;
                float v = acc[mi][ni][r] + bj[ni];
                *(__hip_bfloat16*)(AsB + row * 144 + col * 2) =
                    __float2bfloat16(sigmoidf_(v));
            }
        }
    }
    __syncthreads();

    // ---- coalesced writeout: 64 rows x 128B, 4 threads/row x 32B ----
    {
        const int row = tid >> 2;
        const int ch  = tid & 3;
        const char* srcp = AsB + row * 144 + ch * 32;
        short8v v0 = *(const short8v*)(srcp);
        short8v v1 = *(const short8v*)(srcp + 16);
        __hip_bfloat16* dst = T + (size_t)(m0 + row) * J_ + j0 + ch * 16;
        *(short8v*)dst = v0;
        *((short8v*)(dst + 8)) = v1;
    }
}

// ---------------------------------------------------------------------------
// Kernel 2: per (chunk c, pattern p) affine map of CS steps on u=(h[6], s).
// ---------------------------------------------------------------------------
__global__ __launch_bounds__(256) void scan_pass1(
    const __hip_bfloat16* __restrict__ Tb, const float* __restrict__ epsilon,
    float* __restrict__ G)
{
    const int c = blockIdx.x;
    const int p = threadIdx.x;

    float ep[5];
    #pragma unroll
    for (int l = 0; l < 5; ++l)
        ep[l] = SLS * (1.0f / (1.0f + __expf(-epsilon[p * 5 + l])));

    float hc[7][6];
    float sc[7];
    #pragma unroll
    for (int j = 0; j < 7; ++j) {
        sc[j] = 0.0f;
        #pragma unroll
        for (int i = 0; i < 6; ++i) hc[j][i] = (i == j) ? 1.0f : 0.0f;
    }

    const int t0 = c * CS;
    #pragma unroll
    for (int tt = 0; tt < CS; ++tt) {
        const int t = t0 + tt;
        const uint2* tp = (const uint2*)((const unsigned short*)Tb + (size_t)t * J_ + p * 12);
        uint2 u0 = tp[0], u1 = tp[1], u2 = tp[2];
        float T0[6] = { bl_(u0.x), bh_(u0.x), bl_(u0.y), bh_(u0.y), bl_(u1.x), bh_(u1.x) };
        float T1[6] = { bl_(u1.y), bh_(u1.y), bl_(u2.x), bh_(u2.x), bl_(u2.y), bh_(u2.y) };
        float sT0[6];
        #pragma unroll
        for (int l = 0; l < 6; ++l) sT0[l] = SLS * T0[l];

        #pragma unroll
        for (int j = 0; j < 7; ++j) {
            float m[6];
            m[0] = hc[j][0] * sT0[0];
            #pragma unroll
            for (int i = 1; i < 6; ++i)
                m[i] = fmaf(hc[j][i - 1], T1[i - 1], hc[j][i] * sT0[i]);
            hc[j][0] = m[0] + ((j == 6) ? 1.0f : 0.0f);
            #pragma unroll
            for (int i = 1; i < 6; ++i)
                hc[j][i] = fmaf(m[i - 1], ep[i - 1], m[i]);
            sc[j] += hc[j][5];
        }
    }

    #pragma unroll
    for (int j = 0; j < 7; ++j) {
        #pragma unroll
        for (int i = 0; i < 6; ++i)
            G[((size_t)c * 49 + j * 7 + i) * P_ + p] = hc[j][i];
        G[((size_t)c * 49 + j * 7 + 6) * P_ + p] = sc[j];
    }
}

// ---------------------------------------------------------------------------
// Kernel 3: generic compose level — compose 8 consecutive maps.
// ---------------------------------------------------------------------------
__global__ __launch_bounds__(64) void compose_lvl(
    const float* __restrict__ S, float* __restrict__ Dst)
{
    const int g = blockIdx.x >> 2;
    const int p = (blockIdx.x & 3) * 64 + threadIdx.x;

    float Rh[7][6], Rs[7];
    #pragma unroll
    for (int j = 0; j < 7; ++j) {
        Rs[j] = 0.0f;
        #pragma unroll
        for (int i = 0; i < 6; ++i) Rh[j][i] = (i == j) ? 1.0f : 0.0f;
    }

    for (int cc = 0; cc < 8; ++cc) {
        const int c = g * 8 + cc;
        float Ch[7][6], Csv[7];
        #pragma unroll
        for (int j = 0; j < 7; ++j) {
            #pragma unroll
            for (int i = 0; i < 6; ++i)
                Ch[j][i] = S[((size_t)c * 49 + j * 7 + i) * P_ + p];
            Csv[j] = S[((size_t)c * 49 + j * 7 + 6) * P_ + p];
        }
        float Nh[7][6], Ns[7];
        #pragma unroll
        for (int j = 0; j < 7; ++j) {
            #pragma unroll
            for (int i = 0; i < 6; ++i) {
                float a = (j == 6) ? Ch[6][i] : 0.0f;
                #pragma unroll
                for (int u = 0; u < 6; ++u) a = fmaf(Ch[u][i], Rh[j][u], a);
                Nh[j][i] = a;
            }
            float sa = Rs[j] + ((j == 6) ? Csv[6] : 0.0f);
            #pragma unroll
            for (int u = 0; u < 6; ++u) sa = fmaf(Csv[u], Rh[j][u], sa);
            Ns[j] = sa;
        }
        #pragma unroll
        for (int j = 0; j < 7; ++j) {
            Rs[j] = Ns[j];
            #pragma unroll
            for (int i = 0; i < 6; ++i) Rh[j][i] = Nh[j][i];
        }
    }

    #pragma unroll
    for (int j = 0; j < 7; ++j) {
        #pragma unroll
        for (int i = 0; i < 6; ++i)
            Dst[((size_t)g * 49 + j * 7 + i) * P_ + p] = Rh[j][i];
        Dst[((size_t)g * 49 + j * 7 + 6) * P_ + p] = Rs[j];
    }
}

// ---------------------------------------------------------------------------
// Kernel 4 (fused): apply NL2=8 maps to (h0,0) -> scores, then the MLP head.
// ---------------------------------------------------------------------------
__global__ __launch_bounds__(256) void l2_mlp(
    const float* __restrict__ G3,
    const float* __restrict__ w0, const float* __restrict__ b0,
    const float* __restrict__ w1, const float* __restrict__ b1,
    const float* __restrict__ w2, const float* __restrict__ b2,
    float* __restrict__ out)
{
    __shared__ float s0[H_], z0[H_], z1[H_];
    const int p = threadIdx.x;

    float h[6] = {1.0f, 0.0f, 0.0f, 0.0f, 0.0f, 0.0f};
    float s = 0.0f;
    for (int g = 0; g < NL2; ++g) {
        float Ch[7][6], Csv[7];
        #pragma unroll
        for (int j = 0; j < 7; ++j) {
            #pragma unroll
            for (int i = 0; i < 6; ++i)
                Ch[j][i] = G3[((size_t)g * 49 + j * 7 + i) * P_ + p];
            Csv[j] = G3[((size_t)g * 49 + j * 7 + 6) * P_ + p];
        }
        float nh[6];
        #pragma unroll
        for (int i = 0; i < 6; ++i) {
            float a = Ch[6][i];
            #pragma unroll
            for (int u = 0; u < 6; ++u) a = fmaf(Ch[u][i], h[u], a);
            nh[i] = a;
        }
        float ns = s + Csv[6];
        #pragma unroll
        for (int u = 0; u < 6; ++u) ns = fmaf(Csv[u], h[u], ns);
        #pragma unroll
        for (int i = 0; i < 6; ++i) h[i] = nh[i];
        s = ns;
    }
    s0[p] = s;
    __syncthreads();

    float acc = b0[p];
    {
        const float4* wr = (const float4*)(w0 + (size_t)p * P_);
        #pragma unroll 4
        for (int q = 0; q < P_ / 4; ++q) {
            float4 w = wr[q];
            acc = fmaf(w.x, s0[q * 4 + 0], acc);
            acc = fmaf(w.y, s0[q * 4 + 1], acc);
            acc = fmaf(w.z, s0[q * 4 + 2], acc);
            acc = fmaf(w.w, s0[q * 4 + 3], acc);
        }
    }
    z0[p] = fmaxf(acc, 0.0f);
    __syncthreads();

    acc = b1[p];
    {
        const float4* wr = (const float4*)(w1 + (size_t)p * H_);
        #pragma unroll 4
        for (int q = 0; q < H_ / 4; ++q) {
            float4 w = wr[q];
            acc = fmaf(w.x, z0[q * 4 + 0], acc);
            acc = fmaf(w.y, z0[q * 4 + 1], acc);
            acc = fmaf(w.z, z0[q * 4 + 2], acc);
            acc = fmaf(w.w, z0[q * 4 + 3], acc);
        }
    }
    z1[p] = fmaxf(acc, 0.0f);
    __syncthreads();

    if (p < C_) {
        float o = b2[p];
        const float* wr = w2 + (size_t)p * H_;
        for (int hh = 0; hh < H_; ++hh) o = fmaf(wr[hh], z1[hh], o);
        out[p] = o;
    }
}

// ---------------------------------------------------------------------------
extern "C" void kernel_launch(void* const* d_in, const int* in_sizes, int n_in,
                              void* d_out, int out_size, void* d_ws, size_t ws_size,
                              hipStream_t stream)
{
    const int*   doc     = (const int*)d_in[0];
    const float* emb     = (const float*)d_in[1];
    const float* diags   = (const float*)d_in[2];
    const float* bias    = (const float*)d_in[3];
    const float* epsilon = (const float*)d_in[4];
    const float* w0      = (const float*)d_in[5];
    const float* b0      = (const float*)d_in[6];
    const float* w1      = (const float*)d_in[7];
    const float* b1      = (const float*)d_in[8];
    const float* w2      = (const float*)d_in[9];
    const float* b2      = (const float*)d_in[10];
    float* out = (float*)d_out;

    float* G      = (float*)d_ws;                          // 512*49*256   (25.7 MB)
    float* G2     = G  + (size_t)NCH * 49 * P_;            // 64*49*256    ( 3.2 MB)
    float* G3     = G2 + (size_t)NL1 * 49 * P_;            // 8*49*256     ( 0.4 MB)
    float* fp32_end = G3 + (size_t)NL2 * 49 * P_ + P_;
    __hip_bfloat16* Tb = (__hip_bfloat16*)fp32_end;        // N_*J_ bf16   (25.2 MB)
    __hip_bfloat16* X  = Tb + (size_t)N_ * J_;             // N_*KP bf16   ( 2.6 MB)
    __hip_bfloat16* Bb = X  + (size_t)N_ * KP;             // J_*KP bf16   ( 2.0 MB)

    prep_XB<<<(N_ * KP + J_ * KP) / 256, 256, 0, stream>>>(doc, emb, diags, X, Bb);
    gemm_fullk<<<(N_ / 64) * (J_ / 64), 256, 0, stream>>>(X, Bb, bias, Tb);
    scan_pass1<<<NCH, 256, 0, stream>>>(Tb, epsilon, G);
    compose_lvl<<<(NCH / 8) * 4, 64, 0, stream>>>(G, G2);    // 512 -> 64
    compose_lvl<<<(NL1 / 8) * 4, 64, 0, stream>>>(G2, G3);   // 64  -> 8
    l2_mlp<<<1, 256, 0, stream>>>(G3, w0, b0, w1, b1, w2, b2, out);
}